// Round 4
// baseline (207.945 us; speedup 1.0000x reference)
//
#include <hip/hip_runtime.h>

// SelfAttention: B=4, T=2048, C=D=1024, causal, single head. bf16 MFMA.
// ws (MB): [0 Qb 16][16 Kb 16][32 Vtb 16][48 xb 16][64 Wcat 6][70 S fp32 64][134 P 32]
// R4 = R3 resubmitted verbatim (R3 bench died in infra before push completed).
// qkv+score on counted-vmcnt 256x128 pipelined GEMM (T2+T3+T4+T5):
//  - BK=64, 8 waves (2Mx4N), 96KB LDS double-buffer, 2 phases/K-tile
//  - staging in 3 chunks (A-even, B, A-late); vmcnt(4)/vmcnt(6), never 0
//  - XOR swizzle slot^=(row&7) on 128B LDS rows; inverse-swizzled global src
//  - raw s_barrier (no drain), setprio(1) around MFMA

using u16 = unsigned short;
typedef __attribute__((ext_vector_type(8))) short short8;
typedef __attribute__((ext_vector_type(4))) float f32x4;

__device__ __forceinline__ u16 f2b(float f) {
  unsigned u = __builtin_bit_cast(unsigned, f);
  u += 0x7fffu + ((u >> 16) & 1u);
  return (u16)(u >> 16);
}

__device__ __forceinline__ void async16(void* lds, const void* g) {
  __builtin_amdgcn_global_load_lds(
      (const __attribute__((address_space(1))) unsigned int*)g,
      (__attribute__((address_space(3))) unsigned int*)lds, 16, 0, 0);
}

__device__ __forceinline__ void block_barrier() {
  asm volatile("" ::: "memory");
  __builtin_amdgcn_s_barrier();
  asm volatile("" ::: "memory");
}

__global__ __launch_bounds__(256) void cvt_kernel(const float* __restrict__ in,
                                                  u16* __restrict__ out, int n4) {
  const int i = blockIdx.x * 256 + threadIdx.x;
  if (i >= n4) return;
  const float4 v = reinterpret_cast<const float4*>(in)[i];
  ushort4 o;
  o.x = f2b(v.x); o.y = f2b(v.y); o.z = f2b(v.z); o.w = f2b(v.w);
  reinterpret_cast<ushort4*>(out)[i] = o;
}

__global__ __launch_bounds__(256) void cvt_w3_kernel(const float* __restrict__ Wq,
                                                     const float* __restrict__ Wk,
                                                     const float* __restrict__ Wv,
                                                     u16* __restrict__ Wcat) {
  const int bid = blockIdx.x;  // 3072 blocks
  const int seg = bid >> 10;
  const int i = (bid & 1023) * 256 + threadIdx.x;
  const float* src = seg == 0 ? Wq : (seg == 1 ? Wk : Wv);
  const float4 v = reinterpret_cast<const float4*>(src)[i];
  ushort4 o;
  o.x = f2b(v.x); o.y = f2b(v.y); o.z = f2b(v.z); o.w = f2b(v.w);
  reinterpret_cast<ushort4*>(Wcat + (size_t)seg * 1048576)[i] = o;
}

// ---------------- 256x128 counted-vmcnt pipelined NT-GEMM ----------------
// C[256][128] = A[256xK] * B[128xK]^T  (both row-major, K-contiguous)
// LDS: A 64KB [2buf][2chunk][2sub][64r][64e], B 32KB [2buf][2sub][64r][64e]
// chunk0(E)=rows{0-63,128-191}, chunk1(L)=rows{64-127,192-255}
// swizzle: 16B-slot s of row r stored at phys slot s^(r&7)
#define COMPUTE_PHASE(MQ, READB)                                               \
  {                                                                            \
    const u16* Ab = Asm + buf * 16384 + (MQ)*8192 + arow_off;                  \
    _Pragma("unroll") for (int ii = 0; ii < 4; ++ii) {                         \
      a0[ii] = *(const short8*)(Ab + ii * 1024 + swz0);                        \
      a1[ii] = *(const short8*)(Ab + ii * 1024 + swz1);                        \
    }                                                                          \
    if (READB) {                                                               \
      const u16* Bb = Bsm + buf * 8192 + brow_off;                             \
      _Pragma("unroll") for (int j = 0; j < 2; ++j) {                          \
        bb0[j] = *(const short8*)(Bb + j * 1024 + swz0);                       \
        bb1[j] = *(const short8*)(Bb + j * 1024 + swz1);                       \
      }                                                                        \
    }                                                                          \
    __builtin_amdgcn_s_setprio(1);                                             \
    _Pragma("unroll") for (int ii = 0; ii < 4; ++ii)                           \
        _Pragma("unroll") for (int j = 0; j < 2; ++j)                          \
            acc[(MQ)*4 + ii][j] = __builtin_amdgcn_mfma_f32_16x16x32_bf16(     \
                a0[ii], bb0[j], acc[(MQ)*4 + ii][j], 0, 0, 0);                 \
    _Pragma("unroll") for (int ii = 0; ii < 4; ++ii)                           \
        _Pragma("unroll") for (int j = 0; j < 2; ++j)                          \
            acc[(MQ)*4 + ii][j] = __builtin_amdgcn_mfma_f32_16x16x32_bf16(     \
                a1[ii], bb1[j], acc[(MQ)*4 + ii][j], 0, 0, 0);                 \
    __builtin_amdgcn_s_setprio(0);                                             \
  }

template <typename Epi>
__device__ __forceinline__ void gemm256x128(const u16* __restrict__ A, int lda,
                                            const u16* __restrict__ B, int ldb,
                                            int NT, Epi&& epi) {
  __shared__ __align__(16) char smem[98304];
  u16* const Asm = (u16*)smem;
  u16* const Bsm = (u16*)(smem + 65536);
  const int tid = threadIdx.x;  // 0..511
  const int lane = tid & 63;
  const int w = tid >> 6;
  const int wm = w >> 2;  // 0..1
  const int wn = w & 3;   // 0..3

  f32x4 acc[8][2];
#pragma unroll
  for (int i = 0; i < 8; ++i)
#pragma unroll
    for (int j = 0; j < 2; ++j) acc[i][j] = f32x4{0.f, 0.f, 0.f, 0.f};

  // staging: thread covers (row rr_s, phys 16B-slot tid&7)
  const int rr_s = tid >> 3;  // 0..63
  const int ce = ((tid & 7) ^ (rr_s & 7)) << 3;  // logical elem col (inverse swz)
  const u16* gAe0 = A + (size_t)(0 + rr_s) * lda + ce;
  const u16* gAe1 = A + (size_t)(128 + rr_s) * lda + ce;
  const u16* gAl0 = A + (size_t)(64 + rr_s) * lda + ce;
  const u16* gAl1 = A + (size_t)(192 + rr_s) * lda + ce;
  const u16* gB0 = B + (size_t)(0 + rr_s) * ldb + ce;
  const u16* gB1 = B + (size_t)(64 + rr_s) * ldb + ce;
  u16* const dA = Asm + tid * 8;  // + buf*16384 + chunk*8192 + sub*4096
  u16* const dB = Bsm + tid * 8;  // + buf*8192 + sub*4096

  // prologue: tile 0 -> buf 0, order: AE, B, AL (6 loads)
  async16(dA + 0, gAe0);
  async16(dA + 4096, gAe1);
  async16(dB + 0, gB0);
  async16(dB + 4096, gB1);
  async16(dA + 8192, gAl0);
  async16(dA + 8192 + 4096, gAl1);

  // fragment read offsets (elements)
  const int arow_off = wm * 4096 + (lane & 15) * 64;
  const int brow_off = (wn * 32 + (lane & 15)) * 64;
  const int swz0 = (((lane >> 4)) ^ (lane & 7)) * 8;
  const int swz1 = ((4 + (lane >> 4)) ^ (lane & 7)) * 8;

  short8 a0[4], a1[4], bb0[2], bb1[2];

  for (int t = 0; t < NT; ++t) {
    const int buf = t & 1;
    const int sbuf = buf ^ 1;
    const int ku = (t + 1 < NT ? (t + 1) : (NT - 1)) * 64;
    // ---- phase 0: stage A-E(t+1); compute mq=0 (chunk E + B, cache B) ----
    async16(dA + sbuf * 16384, gAe0 + ku);
    async16(dA + sbuf * 16384 + 4096, gAe1 + ku);
    asm volatile("s_waitcnt vmcnt(4)" ::: "memory");
    block_barrier();
    COMPUTE_PHASE(0, 1)
    // ---- phase 1: stage B(t+1), A-L(t+1); compute mq=1 (chunk L, reuse B) --
    async16(dB + sbuf * 8192, gB0 + ku);
    async16(dB + sbuf * 8192 + 4096, gB1 + ku);
    async16(dA + sbuf * 16384 + 8192, gAl0 + ku);
    async16(dA + sbuf * 16384 + 8192 + 4096, gAl1 + ku);
    asm volatile("s_waitcnt vmcnt(6)" ::: "memory");
    block_barrier();
    COMPUTE_PHASE(1, 0)
  }
  asm volatile("s_waitcnt vmcnt(0)" ::: "memory");  // drain dangling DMA
  epi(acc, wm, wn, lane);
}

// fused QKV: A = xb [8192][1024], B = Wcat [3072][1024]; 768 blocks (32mt x 24nt)
__global__ __launch_bounds__(512) void qkv256_kernel(
    const u16* __restrict__ xb, const u16* __restrict__ Wcat,
    const float* __restrict__ bq, const float* __restrict__ bk,
    const float* __restrict__ bv, u16* __restrict__ Qb, u16* __restrict__ Kb,
    u16* __restrict__ Vtb) {
  const int bid = blockIdx.x;
  const int swz = (bid & 7) * 96 + (bid >> 3);  // XCD swizzle (768 % 8 == 0)
  const int mt = swz / 24, nt = swz % 24;
  const int z = nt >> 3;  // 0:Q 1:K 2:V
  const float* bias = z == 0 ? bq : (z == 1 ? bk : bv);
  gemm256x128(
      xb + (size_t)mt * 256 * 1024, 1024, Wcat + (size_t)nt * 128 * 1024, 1024,
      16, [&](f32x4(&acc)[8][2], int wm, int wn, int lane) {
        const int r0 = mt * 256 + wm * 128 + ((lane >> 4) << 2);
        const int c0 = (nt & 7) * 128 + wn * 32 + (lane & 15);
#pragma unroll
        for (int i4 = 0; i4 < 8; ++i4)
#pragma unroll
          for (int j = 0; j < 2; ++j) {
            const int col = c0 + j * 16;
            const float bb = bias[col];
#pragma unroll
            for (int rr = 0; rr < 4; ++rr) {
              const int row = r0 + i4 * 16 + rr;
              const float v = acc[i4][j][rr] + bb;
              if (z == 0)
                Qb[(size_t)row * 1024 + col] = f2b(v * 0.03125f);
              else if (z == 1)
                Kb[(size_t)row * 1024 + col] = f2b(v);
              else
                Vtb[(size_t)col * 8192 + row] = f2b(v);
            }
          }
      });
}

// causal score tiles 256x128: per batch qt 0..7, kt 0..2qt+1 (72/batch, 288 total)
__global__ __launch_bounds__(512) void score256_kernel(const u16* __restrict__ Qb,
                                                       const u16* __restrict__ Kb,
                                                       float* __restrict__ S) {
  const int bid = blockIdx.x;
  const int b = bid / 72;
  const int r = bid % 72;
  int qt = 0;
  while ((qt + 1) * (qt + 2) <= r) ++qt;
  const int kt = r - qt * (qt + 1);
  float* Sb = S + (size_t)b * 2048 * 2048;
  gemm256x128(
      Qb + ((size_t)b * 2048 + qt * 256) * 1024, 1024,
      Kb + ((size_t)b * 2048 + kt * 128) * 1024, 1024, 16,
      [&](f32x4(&acc)[8][2], int wm, int wn, int lane) {
        const int r0 = qt * 256 + wm * 128 + ((lane >> 4) << 2);
        const int c0 = kt * 128 + wn * 32 + (lane & 15);
#pragma unroll
        for (int i4 = 0; i4 < 8; ++i4)
#pragma unroll
          for (int j = 0; j < 2; ++j)
#pragma unroll
            for (int rr = 0; rr < 4; ++rr)
              Sb[(size_t)(r0 + i4 * 16 + rr) * 2048 + c0 + j * 16] =
                  acc[i4][j][rr];
      });
}

// ---------------- old 128x128 template (kept for pv: variable-K balance) ---
template <typename Epi>
__device__ __forceinline__ void gemm_bt_tile(const u16* __restrict__ A, int lda,
                                             const u16* __restrict__ B, int ldb,
                                             int ksteps, Epi&& epi) {
  __shared__ __align__(16) u16 As[128 * 32];
  __shared__ __align__(16) u16 Bs[128 * 32];
  const int tid = threadIdx.x;
  const int lane = tid & 63;
  const int w = tid >> 6;
  const int wr = (w >> 1) << 6;
  const int wc = (w & 1) << 6;

  f32x4 zero = {0.f, 0.f, 0.f, 0.f};
  f32x4 acc[4][4];
#pragma unroll
  for (int i = 0; i < 4; ++i)
#pragma unroll
    for (int j = 0; j < 4; ++j) acc[i][j] = zero;

  const int sr = tid >> 2;
  const int sc = (tid & 3) << 3;
  const u16* ga0 = A + (size_t)sr * lda + sc;
  const u16* ga1 = A + (size_t)(sr + 64) * lda + sc;
  const u16* gb0 = B + (size_t)sr * ldb + sc;
  const u16* gb1 = B + (size_t)(sr + 64) * ldb + sc;
  u16* la0 = As + tid * 8;
  u16* la1 = As + 2048 + tid * 8;
  u16* lb0 = Bs + tid * 8;
  u16* lb1 = Bs + 2048 + tid * 8;

  const int foff = (lane & 15) * 32 + (lane >> 4) * 8;
  const u16* fa = As + wr * 32 + foff;
  const u16* fb = Bs + wc * 32 + foff;

  for (int ks = 0; ks < ksteps; ++ks) {
    __syncthreads();
    async16(la0, ga0);
    async16(la1, ga1);
    async16(lb0, gb0);
    async16(lb1, gb1);
    ga0 += 32; ga1 += 32; gb0 += 32; gb1 += 32;
    __syncthreads();
    short8 af[4], bf8[4];
#pragma unroll
    for (int i = 0; i < 4; ++i) af[i] = *(const short8*)(fa + (i << 9));
#pragma unroll
    for (int j = 0; j < 4; ++j) bf8[j] = *(const short8*)(fb + (j << 9));
#pragma unroll
    for (int i = 0; i < 4; ++i)
#pragma unroll
      for (int j = 0; j < 4; ++j)
        acc[i][j] = __builtin_amdgcn_mfma_f32_16x16x32_bf16(af[i], bf8[j],
                                                            acc[i][j], 0, 0, 0);
  }
  epi(acc, wr, wc, lane);
}

__global__ __launch_bounds__(256) void softmax_kernel(const float* __restrict__ S,
                                                      u16* __restrict__ P) {
  __shared__ float redm[4], reds[4];
  const int rowid = blockIdx.x;
  const int b = rowid >> 11;
  const int q = rowid & 2047;
  const float* Srow = S + ((size_t)b * 2048 + q) * 2048;
  u16* Prow = P + ((size_t)b * 2048 + q) * 2048;
  const int L = q + 1;
  const int Lpad = ((q >> 7) + 1) << 7;
  const int tid = threadIdx.x;
  float v[8];
  float m = -1e30f;
#pragma unroll
  for (int j = 0; j < 8; ++j) {
    const int k = tid + (j << 8);
    v[j] = (k < L) ? Srow[k] : -1e30f;
    m = fmaxf(m, v[j]);
  }
#pragma unroll
  for (int o = 32; o > 0; o >>= 1) m = fmaxf(m, __shfl_xor(m, o));
  if ((tid & 63) == 0) redm[tid >> 6] = m;
  __syncthreads();
  m = fmaxf(fmaxf(redm[0], redm[1]), fmaxf(redm[2], redm[3]));
  float s = 0.f;
#pragma unroll
  for (int j = 0; j < 8; ++j) {
    const int k = tid + (j << 8);
    const float e = (k < L) ? __expf(v[j] - m) : 0.f;
    v[j] = e;
    s += e;
  }
#pragma unroll
  for (int o = 32; o > 0; o >>= 1) s += __shfl_xor(s, o);
  if ((tid & 63) == 0) reds[tid >> 6] = s;
  __syncthreads();
  s = reds[0] + reds[1] + reds[2] + reds[3];
  const float inv = 1.0f / s;
#pragma unroll
  for (int j = 0; j < 8; ++j) {
    const int k = tid + (j << 8);
    if (k < Lpad) Prow[k] = (k < L) ? f2b(v[j] * inv) : (u16)0;
  }
}

__global__ __launch_bounds__(256) void pv_kernel(const u16* __restrict__ P,
                                                 const u16* __restrict__ Vtb,
                                                 float* __restrict__ O) {
  const int bid = blockIdx.x;  // 512 = 4b x 16qt x 8dt
  const int b = bid >> 7;
  const int r = bid & 127;
  const int qt = r >> 3, dt = r & 7;
  const u16* A = P + (size_t)b * 2048 * 2048 + (size_t)qt * 128 * 2048;
  const u16* Bp = Vtb + (size_t)dt * 128 * 8192 + b * 2048;
  float* Ob = O + (size_t)b * 2048 * 1024;
  gemm_bt_tile(A, 2048, Bp, 8192, (qt + 1) * 4,
               [&](f32x4(&acc)[4][4], int wr, int wc, int lane) {
                 const int r0 = qt * 128 + wr + ((lane >> 4) << 2);
                 const int c0 = dt * 128 + wc + (lane & 15);
#pragma unroll
                 for (int i = 0; i < 4; ++i)
#pragma unroll
                   for (int j = 0; j < 4; ++j)
#pragma unroll
                     for (int rr = 0; rr < 4; ++rr)
                       Ob[(size_t)(r0 + i * 16 + rr) * 1024 + c0 + j * 16] =
                           acc[i][j][rr];
               });
}

extern "C" void kernel_launch(void* const* d_in, const int* in_sizes, int n_in,
                              void* d_out, int out_size, void* d_ws, size_t ws_size,
                              hipStream_t stream) {
  const float* x = (const float*)d_in[0];
  const float* Wq = (const float*)d_in[1];
  const float* bq = (const float*)d_in[2];
  const float* Wk = (const float*)d_in[3];
  const float* bk = (const float*)d_in[4];
  const float* Wv = (const float*)d_in[5];
  const float* bv = (const float*)d_in[6];
  float* out = (float*)d_out;
  char* ws = (char*)d_ws;
  u16* Qb = (u16*)(ws);
  u16* Kb = (u16*)(ws + (16u << 20));
  u16* Vtb = (u16*)(ws + (32u << 20));
  u16* xb = (u16*)(ws + (48u << 20));
  u16* Wcat = (u16*)(ws + (64u << 20));
  float* S = (float*)(ws + (70u << 20));
  u16* P = (u16*)(ws + (134u << 20));

  cvt_kernel<<<8192, 256, 0, stream>>>(x, xb, (8192 * 1024) / 4);
  cvt_w3_kernel<<<3072, 256, 0, stream>>>(Wq, Wk, Wv, Wcat);
  qkv256_kernel<<<768, 512, 0, stream>>>(xb, Wcat, bq, bk, bv, Qb, Kb, Vtb);
  score256_kernel<<<288, 512, 0, stream>>>(Qb, Kb, S);
  softmax_kernel<<<8192, 256, 0, stream>>>(S, P);
  pv_kernel<<<512, 256, 0, stream>>>(P, Vtb, out);
}

// Round 5
// 206.923 us; speedup vs baseline: 1.0049x; 1.0049x over previous
//
#include <hip/hip_runtime.h>

// SelfAttention: B=4, T=2048, C=D=1024, causal, single head. bf16 MFMA.
// ws (MB): [0 Qb 16][16 Kb 16][32 Vtb 16][48 xb 16][64 Wcat 6][70 S fp32 64][134 P 32]
// R5: qkv+score on 256x256 4-phase counted-vmcnt template (verified quadrant):
//  - BK=64, 8 waves (2Mx4N), 128KB LDS 2-buf, 4 half-tile stages/K-tile
//  - phases: {stage half; vmcnt(4); barrier; ds_read subtile; 16 MFMA setprio}
//  - vmcnt never 0 in-loop; ledger-proven guarantee>=2 phases before use
//  - XOR swizzle slot^=(row&7); inverse-swizzled global source (rule 21)

using u16 = unsigned short;
typedef __attribute__((ext_vector_type(8))) short short8;
typedef __attribute__((ext_vector_type(4))) float f32x4;

__device__ __forceinline__ u16 f2b(float f) {
  unsigned u = __builtin_bit_cast(unsigned, f);
  u += 0x7fffu + ((u >> 16) & 1u);
  return (u16)(u >> 16);
}

__device__ __forceinline__ void async16(void* lds, const void* g) {
  __builtin_amdgcn_global_load_lds(
      (const __attribute__((address_space(1))) unsigned int*)g,
      (__attribute__((address_space(3))) unsigned int*)lds, 16, 0, 0);
}

__device__ __forceinline__ void block_barrier() {
  asm volatile("" ::: "memory");
  __builtin_amdgcn_s_barrier();
  asm volatile("" ::: "memory");
}

__global__ __launch_bounds__(256) void cvt_kernel(const float* __restrict__ in,
                                                  u16* __restrict__ out, int n4) {
  const int i = blockIdx.x * 256 + threadIdx.x;
  if (i >= n4) return;
  const float4 v = reinterpret_cast<const float4*>(in)[i];
  ushort4 o;
  o.x = f2b(v.x); o.y = f2b(v.y); o.z = f2b(v.z); o.w = f2b(v.w);
  reinterpret_cast<ushort4*>(out)[i] = o;
}

__global__ __launch_bounds__(256) void cvt_w3_kernel(const float* __restrict__ Wq,
                                                     const float* __restrict__ Wk,
                                                     const float* __restrict__ Wv,
                                                     u16* __restrict__ Wcat) {
  const int bid = blockIdx.x;  // 3072 blocks
  const int seg = bid >> 10;
  const int i = (bid & 1023) * 256 + threadIdx.x;
  const float* src = seg == 0 ? Wq : (seg == 1 ? Wk : Wv);
  const float4 v = reinterpret_cast<const float4*>(src)[i];
  ushort4 o;
  o.x = f2b(v.x); o.y = f2b(v.y); o.z = f2b(v.z); o.w = f2b(v.w);
  reinterpret_cast<ushort4*>(Wcat + (size_t)seg * 1048576)[i] = o;
}

// ---------------- 256x256 4-phase counted-vmcnt NT-GEMM ----------------
// C[256][256] = A[256xK] * B[256xK]^T (row-major, K-contiguous).
// LDS (u16 idx): A buf*16384 + half*8192 ; B same in second 64KB.
// half E = tile rows {0-63,128-191}; half L = {64-127,192-255}  (A)
//        = per-wn cols {+0..31} / {+32..63}                      (B)
// swizzle: 16B-slot s of LDS row r at phys slot s^(r&7).
#define STAGE_AE { async16(dA + sb * 16384, gAE0 + ku); \
                   async16(dA + sb * 16384 + 4096, gAE1 + ku); }
#define STAGE_BE { async16(dB + sb * 16384, gBE0 + ku); \
                   async16(dB + sb * 16384 + 4096, gBE1 + ku); }
#define STAGE_AL { async16(dA + sb * 16384 + 8192, gAL0 + ku); \
                   async16(dA + sb * 16384 + 8192 + 4096, gAL1 + ku); }
#define STAGE_BL { async16(dB + sb * 16384 + 8192, gBL0 + ku); \
                   async16(dB + sb * 16384 + 8192 + 4096, gBL1 + ku); }
#define VW4 asm volatile("s_waitcnt vmcnt(4)" ::: "memory");
#define READ_A(ha)                                                        \
  { const u16* Ab = Asm + buf * 16384 + (ha)*8192 + arow_off;             \
    _Pragma("unroll") for (int ii = 0; ii < 4; ++ii) {                    \
      a[ii][0] = *(const short8*)(Ab + ii * 1024 + swz0);                 \
      a[ii][1] = *(const short8*)(Ab + ii * 1024 + swz1); } }
#define READ_B(hb)                                                        \
  { const u16* Bb = Bsm + buf * 16384 + (hb)*8192 + brow_off;             \
    _Pragma("unroll") for (int jj = 0; jj < 2; ++jj) {                    \
      b[jj][0] = *(const short8*)(Bb + jj * 1024 + swz0);                 \
      b[jj][1] = *(const short8*)(Bb + jj * 1024 + swz1); } }
#define MFMA_Q(ha, hb)                                                    \
  __builtin_amdgcn_s_setprio(1);                                          \
  _Pragma("unroll") for (int ii = 0; ii < 4; ++ii)                        \
  _Pragma("unroll") for (int jj = 0; jj < 2; ++jj) {                      \
    acc[(ha)*4 + ii][(hb)*2 + jj] = __builtin_amdgcn_mfma_f32_16x16x32_bf16( \
        a[ii][0], b[jj][0], acc[(ha)*4 + ii][(hb)*2 + jj], 0, 0, 0);      \
    acc[(ha)*4 + ii][(hb)*2 + jj] = __builtin_amdgcn_mfma_f32_16x16x32_bf16( \
        a[ii][1], b[jj][1], acc[(ha)*4 + ii][(hb)*2 + jj], 0, 0, 0); }    \
  __builtin_amdgcn_s_setprio(0);

template <typename Epi>
__device__ __forceinline__ void gemm256(const u16* __restrict__ A, int lda,
                                        const u16* __restrict__ B, int ldb,
                                        int NT, Epi&& epi) {
  __shared__ __align__(16) char smem[131072];
  u16* const Asm = (u16*)smem;
  u16* const Bsm = (u16*)(smem + 65536);
  const int tid = threadIdx.x;  // 0..511
  const int lane = tid & 63;
  const int w = tid >> 6;
  const int wm = w >> 2;  // 0..1
  const int wn = w & 3;   // 0..3

  f32x4 acc[8][4];
#pragma unroll
  for (int i = 0; i < 8; ++i)
#pragma unroll
    for (int j = 0; j < 4; ++j) acc[i][j] = f32x4{0.f, 0.f, 0.f, 0.f};

  // staging: thread t covers LDS row r128=t>>3 (load0) / r128+64 (load1),
  // phys slot t&7; logical col = (slot ^ (row&7))*8  ((r+64)&7 == r&7)
  const int r128 = tid >> 3;
  const int ce = ((tid & 7) ^ (r128 & 7)) << 3;
  const u16* gAE0 = A + (size_t)(r128)*lda + ce;
  const u16* gAE1 = A + (size_t)(128 + r128) * lda + ce;
  const u16* gAL0 = gAE0 + (size_t)64 * lda;
  const u16* gAL1 = gAE1 + (size_t)64 * lda;
  const int bR0 = ((r128 >> 5) << 6) + (r128 & 31);
  const u16* gBE0 = B + (size_t)bR0 * ldb + ce;
  const u16* gBE1 = B + (size_t)(bR0 + 128) * ldb + ce;
  const u16* gBL0 = gBE0 + (size_t)32 * ldb;
  const u16* gBL1 = gBE1 + (size_t)32 * ldb;
  u16* const dA = Asm + tid * 8;
  u16* const dB = Bsm + tid * 8;

  // prologue: tile 0 -> buf 0, order AE,BE,AL,BL (8 loads in flight)
  {
    const int sb = 0, ku = 0;
    STAGE_AE; STAGE_BE; STAGE_AL; STAGE_BL;
  }

  const int arow_off = wm * 4096 + (lane & 15) * 64;
  const int brow_off = wn * 2048 + (lane & 15) * 64;
  const int swz0 = ((lane >> 4) ^ (lane & 7)) * 8;
  const int swz1 = ((4 + (lane >> 4)) ^ (lane & 7)) * 8;

  short8 a[4][2], b[2][2];

  for (int t = 0; t < NT; ++t) {
    const int buf = t & 1;
    const int sb = buf ^ 1;
    const int ku = (t + 1 < NT ? (t + 1) : (NT - 1)) * 64;
    // P1: quadrant (A-E x B-E)
    STAGE_AE; VW4; block_barrier();
    READ_A(0); READ_B(0); MFMA_Q(0, 0);
    // P2: quadrant (A-E x B-L)   (A regs reused)
    STAGE_BE; VW4; block_barrier();
    READ_B(1); MFMA_Q(0, 1);
    // P3: quadrant (A-L x B-L)   (B regs reused)
    STAGE_AL; VW4; block_barrier();
    READ_A(1); MFMA_Q(1, 1);
    // P4: quadrant (A-L x B-E)   (re-read resident B-E; no wait)
    STAGE_BL; block_barrier();
    READ_B(0); MFMA_Q(1, 0);
  }
  asm volatile("s_waitcnt vmcnt(0)" ::: "memory");  // drain dangling DMA
  epi(acc, wm, wn, lane);
}

// fused QKV: A = xb [8192][1024], B = Wcat [3072][1024]; 384 blocks (32mt x 12nt)
__global__ __launch_bounds__(512, 1) void qkv256_kernel(
    const u16* __restrict__ xb, const u16* __restrict__ Wcat,
    const float* __restrict__ bq, const float* __restrict__ bk,
    const float* __restrict__ bv, u16* __restrict__ Qb, u16* __restrict__ Kb,
    u16* __restrict__ Vtb) {
  const int bid = blockIdx.x;
  const int swz = (bid & 7) * 48 + (bid >> 3);  // XCD swizzle (384 = 8*48)
  const int mt = swz / 12, nt = swz % 12;       // nt fastest: x panel L2 reuse
  const int z = nt >> 2;  // 0:Q 1:K 2:V
  const float* bias = z == 0 ? bq : (z == 1 ? bk : bv);
  gemm256(
      xb + (size_t)mt * 256 * 1024, 1024, Wcat + (size_t)nt * 256 * 1024, 1024,
      16, [&](f32x4(&acc)[8][4], int wm, int wn, int lane) {
        const int r0 = mt * 256 + wm * 128 + ((lane >> 4) << 2);
        const int c0 = (nt & 3) * 256 + wn * 64 + (lane & 15);
#pragma unroll
        for (int ii = 0; ii < 8; ++ii)
#pragma unroll
          for (int n = 0; n < 4; ++n) {
            const int col = c0 + n * 16;
            const float bb = bias[col];
#pragma unroll
            for (int rr = 0; rr < 4; ++rr) {
              const int row = r0 + ii * 16 + rr;
              const float v = acc[ii][n][rr] + bb;
              if (z == 0)
                Qb[(size_t)row * 1024 + col] = f2b(v * 0.03125f);
              else if (z == 1)
                Kb[(size_t)row * 1024 + col] = f2b(v);
              else
                Vtb[(size_t)col * 8192 + row] = f2b(v);
            }
          }
      });
}

// causal score 256x256 tiles: per batch qt 0..7, kt 0..qt (36/batch, 144 total)
__global__ __launch_bounds__(512, 1) void score256_kernel(
    const u16* __restrict__ Qb, const u16* __restrict__ Kb,
    float* __restrict__ S) {
  const int bid = blockIdx.x;
  const int swz = (bid & 7) * 18 + (bid >> 3);  // 144 = 8*18
  const int b = swz / 36;
  const int r = swz % 36;
  int qt = 0;
  while ((qt + 1) * (qt + 2) / 2 <= r) ++qt;
  const int kt = r - qt * (qt + 1) / 2;
  float* Sb = S + (size_t)b * 2048 * 2048;
  gemm256(
      Qb + ((size_t)b * 2048 + qt * 256) * 1024, 1024,
      Kb + ((size_t)b * 2048 + kt * 256) * 1024, 1024, 16,
      [&](f32x4(&acc)[8][4], int wm, int wn, int lane) {
        const int r0 = qt * 256 + wm * 128 + ((lane >> 4) << 2);
        const int c0 = kt * 256 + wn * 64 + (lane & 15);
#pragma unroll
        for (int ii = 0; ii < 8; ++ii)
#pragma unroll
          for (int n = 0; n < 4; ++n)
#pragma unroll
            for (int rr = 0; rr < 4; ++rr)
              Sb[(size_t)(r0 + ii * 16 + rr) * 2048 + c0 + n * 16] =
                  acc[ii][n][rr];
      });
}

// ---------------- old 128x128 template (pv: variable-K balance) ----------
template <typename Epi>
__device__ __forceinline__ void gemm_bt_tile(const u16* __restrict__ A, int lda,
                                             const u16* __restrict__ B, int ldb,
                                             int ksteps, Epi&& epi) {
  __shared__ __align__(16) u16 As[128 * 32];
  __shared__ __align__(16) u16 Bs[128 * 32];
  const int tid = threadIdx.x;
  const int lane = tid & 63;
  const int w = tid >> 6;
  const int wr = (w >> 1) << 6;
  const int wc = (w & 1) << 6;

  f32x4 zero = {0.f, 0.f, 0.f, 0.f};
  f32x4 acc[4][4];
#pragma unroll
  for (int i = 0; i < 4; ++i)
#pragma unroll
    for (int j = 0; j < 4; ++j) acc[i][j] = zero;

  const int sr = tid >> 2;
  const int sc = (tid & 3) << 3;
  const u16* ga0 = A + (size_t)sr * lda + sc;
  const u16* ga1 = A + (size_t)(sr + 64) * lda + sc;
  const u16* gb0 = B + (size_t)sr * ldb + sc;
  const u16* gb1 = B + (size_t)(sr + 64) * ldb + sc;
  u16* la0 = As + tid * 8;
  u16* la1 = As + 2048 + tid * 8;
  u16* lb0 = Bs + tid * 8;
  u16* lb1 = Bs + 2048 + tid * 8;

  const int foff = (lane & 15) * 32 + (lane >> 4) * 8;
  const u16* fa = As + wr * 32 + foff;
  const u16* fb = Bs + wc * 32 + foff;

  for (int ks = 0; ks < ksteps; ++ks) {
    __syncthreads();
    async16(la0, ga0);
    async16(la1, ga1);
    async16(lb0, gb0);
    async16(lb1, gb1);
    ga0 += 32; ga1 += 32; gb0 += 32; gb1 += 32;
    __syncthreads();
    short8 af[4], bf8[4];
#pragma unroll
    for (int i = 0; i < 4; ++i) af[i] = *(const short8*)(fa + (i << 9));
#pragma unroll
    for (int j = 0; j < 4; ++j) bf8[j] = *(const short8*)(fb + (j << 9));
#pragma unroll
    for (int i = 0; i < 4; ++i)
#pragma unroll
      for (int j = 0; j < 4; ++j)
        acc[i][j] = __builtin_amdgcn_mfma_f32_16x16x32_bf16(af[i], bf8[j],
                                                            acc[i][j], 0, 0, 0);
  }
  epi(acc, wr, wc, lane);
}

__global__ __launch_bounds__(256) void softmax_kernel(const float* __restrict__ S,
                                                      u16* __restrict__ P) {
  __shared__ float redm[4], reds[4];
  const int rowid = blockIdx.x;
  const int b = rowid >> 11;
  const int q = rowid & 2047;
  const float* Srow = S + ((size_t)b * 2048 + q) * 2048;
  u16* Prow = P + ((size_t)b * 2048 + q) * 2048;
  const int L = q + 1;
  const int Lpad = ((q >> 7) + 1) << 7;
  const int tid = threadIdx.x;
  float v[8];
  float m = -1e30f;
#pragma unroll
  for (int j = 0; j < 8; ++j) {
    const int k = tid + (j << 8);
    v[j] = (k < L) ? Srow[k] : -1e30f;
    m = fmaxf(m, v[j]);
  }
#pragma unroll
  for (int o = 32; o > 0; o >>= 1) m = fmaxf(m, __shfl_xor(m, o));
  if ((tid & 63) == 0) redm[tid >> 6] = m;
  __syncthreads();
  m = fmaxf(fmaxf(redm[0], redm[1]), fmaxf(redm[2], redm[3]));
  float s = 0.f;
#pragma unroll
  for (int j = 0; j < 8; ++j) {
    const int k = tid + (j << 8);
    const float e = (k < L) ? __expf(v[j] - m) : 0.f;
    v[j] = e;
    s += e;
  }
#pragma unroll
  for (int o = 32; o > 0; o >>= 1) s += __shfl_xor(s, o);
  if ((tid & 63) == 0) reds[tid >> 6] = s;
  __syncthreads();
  s = reds[0] + reds[1] + reds[2] + reds[3];
  const float inv = 1.0f / s;
#pragma unroll
  for (int j = 0; j < 8; ++j) {
    const int k = tid + (j << 8);
    if (k < Lpad) Prow[k] = (k < L) ? f2b(v[j] * inv) : (u16)0;
  }
}

__global__ __launch_bounds__(256) void pv_kernel(const u16* __restrict__ P,
                                                 const u16* __restrict__ Vtb,
                                                 float* __restrict__ O) {
  const int bid = blockIdx.x;  // 512 = 4b x 16qt x 8dt
  const int b = bid >> 7;
  const int r = bid & 127;
  const int qt = r >> 3, dt = r & 7;
  const u16* A = P + (size_t)b * 2048 * 2048 + (size_t)qt * 128 * 2048;
  const u16* Bp = Vtb + (size_t)dt * 128 * 8192 + b * 2048;
  float* Ob = O + (size_t)b * 2048 * 1024;
  gemm_bt_tile(A, 2048, Bp, 8192, (qt + 1) * 4,
               [&](f32x4(&acc)[4][4], int wr, int wc, int lane) {
                 const int r0 = qt * 128 + wr + ((lane >> 4) << 2);
                 const int c0 = dt * 128 + wc + (lane & 15);
#pragma unroll
                 for (int i = 0; i < 4; ++i)
#pragma unroll
                   for (int j = 0; j < 4; ++j)
#pragma unroll
                     for (int rr = 0; rr < 4; ++rr)
                       Ob[(size_t)(r0 + i * 16 + rr) * 1024 + c0 + j * 16] =
                           acc[i][j][rr];
               });
}

extern "C" void kernel_launch(void* const* d_in, const int* in_sizes, int n_in,
                              void* d_out, int out_size, void* d_ws, size_t ws_size,
                              hipStream_t stream) {
  const float* x = (const float*)d_in[0];
  const float* Wq = (const float*)d_in[1];
  const float* bq = (const float*)d_in[2];
  const float* Wk = (const float*)d_in[3];
  const float* bk = (const float*)d_in[4];
  const float* Wv = (const float*)d_in[5];
  const float* bv = (const float*)d_in[6];
  float* out = (float*)d_out;
  char* ws = (char*)d_ws;
  u16* Qb = (u16*)(ws);
  u16* Kb = (u16*)(ws + (16u << 20));
  u16* Vtb = (u16*)(ws + (32u << 20));
  u16* xb = (u16*)(ws + (48u << 20));
  u16* Wcat = (u16*)(ws + (64u << 20));
  float* S = (float*)(ws + (70u << 20));
  u16* P = (u16*)(ws + (134u << 20));

  cvt_kernel<<<8192, 256, 0, stream>>>(x, xb, (8192 * 1024) / 4);
  cvt_w3_kernel<<<3072, 256, 0, stream>>>(Wq, Wk, Wv, Wcat);
  qkv256_kernel<<<384, 512, 0, stream>>>(xb, Wcat, bq, bk, bv, Qb, Kb, Vtb);
  score256_kernel<<<144, 512, 0, stream>>>(Qb, Kb, S);
  softmax_kernel<<<8192, 256, 0, stream>>>(S, P);
  pv_kernel<<<512, 256, 0, stream>>>(P, Vtb, out);
}

// Round 6
// 179.194 us; speedup vs baseline: 1.1604x; 1.1547x over previous
//
#include <hip/hip_runtime.h>

// SelfAttention: B=4, T=2048, C=D=1024, causal, single head. bf16 MFMA.
// ws (MB): [0 Qb 16][16 Kb 16][32 Vtb 16][48 xb 16][64 Wcat 6][70 S bf16 32][134 P 32]
// R6: revert qkv/score to the measured-best m97-style 128x128 template (R2:
// qkv=72us). New: (1) pv grid remapped so each CU gets complementary qt work
// (fixes 2x tail imbalance), (2) S stored bf16 + softmax fully short8-
// vectorized, (3) single W-convert launch.

using u16 = unsigned short;
typedef __attribute__((ext_vector_type(8))) short short8;
typedef __attribute__((ext_vector_type(4))) float f32x4;

__device__ __forceinline__ u16 f2b(float f) {
  unsigned u = __builtin_bit_cast(unsigned, f);
  u += 0x7fffu + ((u >> 16) & 1u);
  return (u16)(u >> 16);
}

__device__ __forceinline__ float b2f(u16 h) {
  return __builtin_bit_cast(float, (unsigned)h << 16);
}

__device__ __forceinline__ void async16(void* lds, const void* g) {
  __builtin_amdgcn_global_load_lds(
      (const __attribute__((address_space(1))) unsigned int*)g,
      (__attribute__((address_space(3))) unsigned int*)lds, 16, 0, 0);
}

__global__ __launch_bounds__(256) void cvt_kernel(const float* __restrict__ in,
                                                  u16* __restrict__ out, int n4) {
  const int i = blockIdx.x * 256 + threadIdx.x;
  if (i >= n4) return;
  const float4 v = reinterpret_cast<const float4*>(in)[i];
  ushort4 o;
  o.x = f2b(v.x); o.y = f2b(v.y); o.z = f2b(v.z); o.w = f2b(v.w);
  reinterpret_cast<ushort4*>(out)[i] = o;
}

__global__ __launch_bounds__(256) void cvt_w3_kernel(const float* __restrict__ Wq,
                                                     const float* __restrict__ Wk,
                                                     const float* __restrict__ Wv,
                                                     u16* __restrict__ Wcat) {
  const int bid = blockIdx.x;  // 3072 blocks
  const int seg = bid >> 10;
  const int i = (bid & 1023) * 256 + threadIdx.x;
  const float* src = seg == 0 ? Wq : (seg == 1 ? Wk : Wv);
  const float4 v = reinterpret_cast<const float4*>(src)[i];
  ushort4 o;
  o.x = f2b(v.x); o.y = f2b(v.y); o.z = f2b(v.z); o.w = f2b(v.w);
  reinterpret_cast<ushort4*>(Wcat + (size_t)seg * 1048576)[i] = o;
}

// C[m][n] = sum_k A[m][k] * B[n][k]; 128x128 tile, BK=32, 4 waves (2x2 of 64x64).
// A-frag: row=lane&15, k=8*(lane>>4)+j ; B-frag: col=lane&15, k=8*(lane>>4)+j
// D-frag: col=lane&15, row=4*(lane>>4)+rr   (guide §3, HW-verified m89/m91)
template <typename Epi>
__device__ __forceinline__ void gemm_bt_tile(const u16* __restrict__ A, int lda,
                                             const u16* __restrict__ B, int ldb,
                                             int ksteps, Epi&& epi) {
  __shared__ __align__(16) u16 As[128 * 32];
  __shared__ __align__(16) u16 Bs[128 * 32];
  const int tid = threadIdx.x;
  const int lane = tid & 63;
  const int w = tid >> 6;
  const int wr = (w >> 1) << 6;
  const int wc = (w & 1) << 6;

  f32x4 zero = {0.f, 0.f, 0.f, 0.f};
  f32x4 acc[4][4];
#pragma unroll
  for (int i = 0; i < 4; ++i)
#pragma unroll
    for (int j = 0; j < 4; ++j) acc[i][j] = zero;

  const int sr = tid >> 2;
  const int sc = (tid & 3) << 3;
  const u16* ga0 = A + (size_t)sr * lda + sc;
  const u16* ga1 = A + (size_t)(sr + 64) * lda + sc;
  const u16* gb0 = B + (size_t)sr * ldb + sc;
  const u16* gb1 = B + (size_t)(sr + 64) * ldb + sc;
  u16* la0 = As + tid * 8;
  u16* la1 = As + 2048 + tid * 8;
  u16* lb0 = Bs + tid * 8;
  u16* lb1 = Bs + 2048 + tid * 8;

  const int foff = (lane & 15) * 32 + (lane >> 4) * 8;
  const u16* fa = As + wr * 32 + foff;
  const u16* fb = Bs + wc * 32 + foff;

  for (int ks = 0; ks < ksteps; ++ks) {
    __syncthreads();
    async16(la0, ga0);
    async16(la1, ga1);
    async16(lb0, gb0);
    async16(lb1, gb1);
    ga0 += 32; ga1 += 32; gb0 += 32; gb1 += 32;
    __syncthreads();
    short8 af[4], bf8[4];
#pragma unroll
    for (int i = 0; i < 4; ++i) af[i] = *(const short8*)(fa + (i << 9));
#pragma unroll
    for (int j = 0; j < 4; ++j) bf8[j] = *(const short8*)(fb + (j << 9));
#pragma unroll
    for (int i = 0; i < 4; ++i)
#pragma unroll
      for (int j = 0; j < 4; ++j)
        acc[i][j] = __builtin_amdgcn_mfma_f32_16x16x32_bf16(af[i], bf8[j],
                                                            acc[i][j], 0, 0, 0);
  }
  epi(acc, wr, wc, lane);
}

// bid 0..511: Q (x @ Wq^T, scaled 1/32); 512..1023: K; 1024..1535: Vt = Wv @ x^T
__global__ __launch_bounds__(256) void qkv_kernel(
    const u16* __restrict__ xb, const u16* __restrict__ Wcat,
    const float* __restrict__ bq, const float* __restrict__ bk,
    const float* __restrict__ bv, u16* __restrict__ Qb, u16* __restrict__ Kb,
    u16* __restrict__ Vtb) {
  const int bid = blockIdx.x;
  const int z = bid >> 9;
  const int r = bid & 511;
  if (z < 2) {
    const int mt = r >> 3, nt = r & 7;  // 64 x 8 tiles over (8192 x 1024)
    const u16* W = Wcat + (size_t)z * 1048576;
    const float* bias = z ? bk : bq;
    u16* out = z ? Kb : Qb;
    const float scale = z ? 1.0f : 0.03125f;  // Q pre-scaled by 1/sqrt(1024)
    gemm_bt_tile(
        xb + (size_t)mt * 128 * 1024, 1024, W + (size_t)nt * 128 * 1024, 1024, 32,
        [&](f32x4(&acc)[4][4], int wr, int wc, int lane) {
          const int r0 = mt * 128 + wr + ((lane >> 4) << 2);
          const int c0 = nt * 128 + wc + (lane & 15);
#pragma unroll
          for (int i = 0; i < 4; ++i)
#pragma unroll
            for (int j = 0; j < 4; ++j) {
              const int col = c0 + j * 16;
              const float bb = bias[col];
#pragma unroll
              for (int rr = 0; rr < 4; ++rr)
                out[(size_t)(r0 + i * 16 + rr) * 1024 + col] =
                    f2b((acc[i][j][rr] + bb) * scale);
            }
        });
  } else {
    const int mt = r >> 6, nt = r & 63;  // 8 x 64 tiles over (1024 x 8192)
    const u16* Wvb = Wcat + (size_t)2 * 1048576;
    gemm_bt_tile(
        Wvb + (size_t)mt * 128 * 1024, 1024, xb + (size_t)nt * 128 * 1024, 1024, 32,
        [&](f32x4(&acc)[4][4], int wr, int wc, int lane) {
          const int r0 = mt * 128 + wr + ((lane >> 4) << 2);
          const int c0 = nt * 128 + wc + (lane & 15);
#pragma unroll
          for (int i = 0; i < 4; ++i)
#pragma unroll
            for (int rr = 0; rr < 4; ++rr) {
              const int row = r0 + i * 16 + rr;  // d index
              const float bb = bv[row];
#pragma unroll
              for (int j = 0; j < 4; ++j)
                Vtb[(size_t)row * 8192 + c0 + j * 16] = f2b(acc[i][j][rr] + bb);
            }
        });
  }
}

// lower-triangle tiles only: grid (136, 4); S stored bf16
__global__ __launch_bounds__(256) void score_kernel(const u16* __restrict__ Qb,
                                                    const u16* __restrict__ Kb,
                                                    u16* __restrict__ S) {
  const int b = blockIdx.y;
  const int t = blockIdx.x;
  int qt = 0;
  while ((qt + 1) * (qt + 2) / 2 <= t) ++qt;
  const int kt = t - (qt * (qt + 1)) / 2;
  const u16* A = Qb + ((size_t)b * 2048 + qt * 128) * 1024;
  const u16* Bp = Kb + ((size_t)b * 2048 + kt * 128) * 1024;
  u16* Sb = S + (size_t)b * 2048 * 2048;
  gemm_bt_tile(A, 1024, Bp, 1024, 32,
               [&](f32x4(&acc)[4][4], int wr, int wc, int lane) {
                 const int r0 = qt * 128 + wr + ((lane >> 4) << 2);
                 const int c0 = kt * 128 + wc + (lane & 15);
#pragma unroll
                 for (int i = 0; i < 4; ++i)
#pragma unroll
                   for (int j = 0; j < 4; ++j)
#pragma unroll
                     for (int rr = 0; rr < 4; ++rr)
                       Sb[(size_t)(r0 + i * 16 + rr) * 2048 + c0 + j * 16] =
                           f2b(acc[i][j][rr]);
               });
}

// one block per row; bf16 S in, bf16 P out; fully short8-vectorized.
// thread t owns 8 contiguous k: [t*8, t*8+8)
__global__ __launch_bounds__(256) void softmax_kernel(const u16* __restrict__ S,
                                                      u16* __restrict__ P) {
  __shared__ float redm[4], reds[4];
  const int rowid = blockIdx.x;
  const int b = rowid >> 11;
  const int q = rowid & 2047;
  const u16* Srow = S + ((size_t)b * 2048 + q) * 2048;
  u16* Prow = P + ((size_t)b * 2048 + q) * 2048;
  const int L = q + 1;
  const int Lpad = ((q >> 7) + 1) << 7;  // multiple of 128; k0 chunks don't straddle
  const int tid = threadIdx.x;
  const int k0 = tid << 3;
  const bool active = k0 < Lpad;
  float v[8];
  float m = -1e30f;
  if (active) {
    const short8 s8 = *(const short8*)(Srow + k0);
#pragma unroll
    for (int j = 0; j < 8; ++j) {
      v[j] = (k0 + j < L) ? b2f((u16)s8[j]) : -1e30f;
      m = fmaxf(m, v[j]);
    }
  }
#pragma unroll
  for (int o = 32; o > 0; o >>= 1) m = fmaxf(m, __shfl_xor(m, o));
  if ((tid & 63) == 0) redm[tid >> 6] = m;
  __syncthreads();
  m = fmaxf(fmaxf(redm[0], redm[1]), fmaxf(redm[2], redm[3]));
  float s = 0.f;
  if (active) {
#pragma unroll
    for (int j = 0; j < 8; ++j) {
      const float e = (k0 + j < L) ? __expf(v[j] - m) : 0.f;
      v[j] = e;
      s += e;
    }
  }
#pragma unroll
  for (int o = 32; o > 0; o >>= 1) s += __shfl_xor(s, o);
  if ((tid & 63) == 0) reds[tid >> 6] = s;
  __syncthreads();
  s = reds[0] + reds[1] + reds[2] + reds[3];
  const float inv = 1.0f / s;
  if (active) {
    short8 o8;
#pragma unroll
    for (int j = 0; j < 8; ++j)
      o8[j] = (short)((k0 + j < L) ? f2b(v[j] * inv) : (u16)0);
    *(short8*)(Prow + k0) = o8;
  }
}

// O = P @ V using Vt[d][t]; K-loop truncated by causality.
// Grid remap: bid<256 -> b in {0,1}, qt ascending; bid>=256 -> b in {2,3},
// qt = 15-qt_raw, so CU-paired blocks (bid, bid+256) total constant work.
__global__ __launch_bounds__(256) void pv_kernel(const u16* __restrict__ P,
                                                 const u16* __restrict__ Vtb,
                                                 float* __restrict__ O) {
  const int bid = blockIdx.x;  // 512
  const int pair = bid >> 8;
  const int idx = bid & 255;
  const int hb = idx >> 7;
  const int qt_raw = (idx >> 3) & 15;
  const int dt = idx & 7;
  const int qt = pair ? (15 - qt_raw) : qt_raw;
  const int b = pair * 2 + hb;
  const u16* A = P + (size_t)b * 2048 * 2048 + (size_t)qt * 128 * 2048;
  const u16* Bp = Vtb + (size_t)dt * 128 * 8192 + b * 2048;
  float* Ob = O + (size_t)b * 2048 * 1024;
  gemm_bt_tile(A, 2048, Bp, 8192, (qt + 1) * 4,
               [&](f32x4(&acc)[4][4], int wr, int wc, int lane) {
                 const int r0 = qt * 128 + wr + ((lane >> 4) << 2);
                 const int c0 = dt * 128 + wc + (lane & 15);
#pragma unroll
                 for (int i = 0; i < 4; ++i)
#pragma unroll
                   for (int j = 0; j < 4; ++j)
#pragma unroll
                     for (int rr = 0; rr < 4; ++rr)
                       Ob[(size_t)(r0 + i * 16 + rr) * 1024 + c0 + j * 16] =
                           acc[i][j][rr];
               });
}

extern "C" void kernel_launch(void* const* d_in, const int* in_sizes, int n_in,
                              void* d_out, int out_size, void* d_ws, size_t ws_size,
                              hipStream_t stream) {
  const float* x = (const float*)d_in[0];
  const float* Wq = (const float*)d_in[1];
  const float* bq = (const float*)d_in[2];
  const float* Wk = (const float*)d_in[3];
  const float* bk = (const float*)d_in[4];
  const float* Wv = (const float*)d_in[5];
  const float* bv = (const float*)d_in[6];
  float* out = (float*)d_out;
  char* ws = (char*)d_ws;
  u16* Qb = (u16*)(ws);
  u16* Kb = (u16*)(ws + (16u << 20));
  u16* Vtb = (u16*)(ws + (32u << 20));
  u16* xb = (u16*)(ws + (48u << 20));
  u16* Wcat = (u16*)(ws + (64u << 20));
  u16* S = (u16*)(ws + (70u << 20));
  u16* P = (u16*)(ws + (134u << 20));

  cvt_kernel<<<8192, 256, 0, stream>>>(x, xb, (8192 * 1024) / 4);
  cvt_w3_kernel<<<3072, 256, 0, stream>>>(Wq, Wk, Wv, Wcat);
  qkv_kernel<<<1536, 256, 0, stream>>>(xb, Wcat, bq, bk, bv, Qb, Kb, Vtb);
  score_kernel<<<dim3(136, 4), 256, 0, stream>>>(Qb, Kb, S);
  softmax_kernel<<<8192, 256, 0, stream>>>(S, P);
  pv_kernel<<<512, 256, 0, stream>>>(P, Vtb, out);
}

// Round 7
// 169.982 us; speedup vs baseline: 1.2233x; 1.0542x over previous
//
#include <hip/hip_runtime.h>

// SelfAttention: B=4, T=2048, C=D=1024, causal, single head. bf16 MFMA.
// ws (MB): [0 Qb 16][16 Kb 16][32 Vtb 16][48 xb 16][64 Wcat 6][70 S bf16 32][134 P 32]
// R7: keep R6 pipeline; gemm template BK=32 -> BK=64 (halved barrier/drain
// count) + XOR swizzle slot^=(row&7) on 128B LDS rows with inverse-swizzled
// global_load_lds source (R4/R5-verified: 0 bank conflicts). cvt launches
// merged. Structure otherwise the measured-best m97-style 128x128, 4 waves.

using u16 = unsigned short;
typedef __attribute__((ext_vector_type(8))) short short8;
typedef __attribute__((ext_vector_type(4))) float f32x4;

__device__ __forceinline__ u16 f2b(float f) {
  unsigned u = __builtin_bit_cast(unsigned, f);
  u += 0x7fffu + ((u >> 16) & 1u);
  return (u16)(u >> 16);
}

__device__ __forceinline__ float b2f(u16 h) {
  return __builtin_bit_cast(float, (unsigned)h << 16);
}

__device__ __forceinline__ void async16(void* lds, const void* g) {
  __builtin_amdgcn_global_load_lds(
      (const __attribute__((address_space(1))) unsigned int*)g,
      (__attribute__((address_space(3))) unsigned int*)lds, 16, 0, 0);
}

// one launch: x (8192x1024) + Wq,Wk,Wv (1024x1024 each) -> bf16
__global__ __launch_bounds__(256) void cvt_all_kernel(
    const float* __restrict__ x, const float* __restrict__ Wq,
    const float* __restrict__ Wk, const float* __restrict__ Wv,
    u16* __restrict__ xb, u16* __restrict__ Wcat) {
  const int i = blockIdx.x * 256 + threadIdx.x;  // float4 chunk index
  const float* src;
  u16* dst;
  int c;
  if (i < 2097152) {  // 8192*1024/4
    src = x; dst = xb; c = i;
  } else {
    const int r = i - 2097152;
    const int seg = r >> 18;  // 1024*1024/4 = 262144 chunks per W
    src = seg == 0 ? Wq : (seg == 1 ? Wk : Wv);
    dst = Wcat + (size_t)seg * 1048576;
    c = r & 262143;
  }
  const float4 v = reinterpret_cast<const float4*>(src)[c];
  ushort4 o;
  o.x = f2b(v.x); o.y = f2b(v.y); o.z = f2b(v.z); o.w = f2b(v.w);
  reinterpret_cast<ushort4*>(dst)[c] = o;
}

// C[m][n] = sum_k A[m][k]*B[n][k]; 128x128 tile, BK=64, 4 waves (2x2 of 64x64).
// LDS [128 rows][8 slots of 8 elems]; 16B-slot s of row r at phys slot s^(r&7);
// global source pre-inverse-swizzled (rule 21). Frag reads conflict-free.
// A-frag: row=lane&15, k=8*(lane>>4)+j+32*kk ; D-frag: col=lane&15,
// row=4*(lane>>4)+rr (HW-verified m89/m91).
template <typename Epi>
__device__ __forceinline__ void gemm_bt_tile(const u16* __restrict__ A, int lda,
                                             const u16* __restrict__ B, int ldb,
                                             int nt, Epi&& epi) {
  __shared__ __align__(16) u16 As[128 * 64];
  __shared__ __align__(16) u16 Bs[128 * 64];
  const int tid = threadIdx.x;
  const int lane = tid & 63;
  const int w = tid >> 6;
  const int wr = (w >> 1) << 6;
  const int wc = (w & 1) << 6;

  f32x4 acc[4][4];
#pragma unroll
  for (int i = 0; i < 4; ++i)
#pragma unroll
    for (int j = 0; j < 4; ++j) acc[i][j] = f32x4{0.f, 0.f, 0.f, 0.f};

  // staging: slot s covers rows s*32..s*32+31; thread t -> row s*32+(t>>3),
  // phys 16B-slot t&7, logical col = ((t&7)^(row&7))*8  (32%8==0 -> row&7
  // invariant across s)
  const int sr = tid >> 3;
  const int ce = ((tid & 7) ^ (sr & 7)) << 3;
  const u16* gA = A + (size_t)sr * lda + ce;
  const u16* gB = B + (size_t)sr * ldb + ce;
  u16* const dA = As + tid * 8;
  u16* const dB = Bs + tid * 8;

  const int hi = lane >> 4;
  const int lo7 = lane & 7;
  const int ra = (wr + (lane & 15)) << 6;  // *64
  const int rb = (wc + (lane & 15)) << 6;
  const int sk0 = (hi ^ lo7) << 3;        // kk=0: logical slot hi
  const int sk1 = ((4 + hi) ^ lo7) << 3;  // kk=1: logical slot 4+hi

  for (int t = 0; t < nt; ++t) {
    __syncthreads();  // all waves done reading previous tile
#pragma unroll
    for (int s = 0; s < 4; ++s) {
      async16(dA + s * 2048, gA + (size_t)(s * 32) * lda);
      async16(dB + s * 2048, gB + (size_t)(s * 32) * ldb);
    }
    gA += 64;
    gB += 64;
    __syncthreads();  // tile staged (compiler drains vmcnt before barrier)
#pragma unroll
    for (int kk = 0; kk < 2; ++kk) {
      const int sk = kk ? sk1 : sk0;
      short8 af[4], bf[4];
#pragma unroll
      for (int i = 0; i < 4; ++i)
        af[i] = *(const short8*)(As + ra + i * 1024 + sk);
#pragma unroll
      for (int j = 0; j < 4; ++j)
        bf[j] = *(const short8*)(Bs + rb + j * 1024 + sk);
#pragma unroll
      for (int i = 0; i < 4; ++i)
#pragma unroll
        for (int j = 0; j < 4; ++j)
          acc[i][j] = __builtin_amdgcn_mfma_f32_16x16x32_bf16(af[i], bf[j],
                                                              acc[i][j], 0, 0, 0);
    }
  }
  epi(acc, wr, wc, lane);
}

// bid 0..511: Q (x @ Wq^T, scaled 1/32); 512..1023: K; 1024..1535: Vt = Wv @ x^T
__global__ __launch_bounds__(256) void qkv_kernel(
    const u16* __restrict__ xb, const u16* __restrict__ Wcat,
    const float* __restrict__ bq, const float* __restrict__ bk,
    const float* __restrict__ bv, u16* __restrict__ Qb, u16* __restrict__ Kb,
    u16* __restrict__ Vtb) {
  const int bid = blockIdx.x;
  const int z = bid >> 9;
  const int r = bid & 511;
  if (z < 2) {
    const int mt = r >> 3, nt = r & 7;  // 64 x 8 tiles over (8192 x 1024)
    const u16* W = Wcat + (size_t)z * 1048576;
    const float* bias = z ? bk : bq;
    u16* out = z ? Kb : Qb;
    const float scale = z ? 1.0f : 0.03125f;  // Q pre-scaled by 1/sqrt(1024)
    gemm_bt_tile(
        xb + (size_t)mt * 128 * 1024, 1024, W + (size_t)nt * 128 * 1024, 1024, 16,
        [&](f32x4(&acc)[4][4], int wr, int wc, int lane) {
          const int r0 = mt * 128 + wr + ((lane >> 4) << 2);
          const int c0 = nt * 128 + wc + (lane & 15);
#pragma unroll
          for (int i = 0; i < 4; ++i)
#pragma unroll
            for (int j = 0; j < 4; ++j) {
              const int col = c0 + j * 16;
              const float bb = bias[col];
#pragma unroll
              for (int rr = 0; rr < 4; ++rr)
                out[(size_t)(r0 + i * 16 + rr) * 1024 + col] =
                    f2b((acc[i][j][rr] + bb) * scale);
            }
        });
  } else {
    const int mt = r >> 6, nt = r & 63;  // 8 x 64 tiles over (1024 x 8192)
    const u16* Wvb = Wcat + (size_t)2 * 1048576;
    gemm_bt_tile(
        Wvb + (size_t)mt * 128 * 1024, 1024, xb + (size_t)nt * 128 * 1024, 1024, 16,
        [&](f32x4(&acc)[4][4], int wr, int wc, int lane) {
          const int r0 = mt * 128 + wr + ((lane >> 4) << 2);
          const int c0 = nt * 128 + wc + (lane & 15);
#pragma unroll
          for (int i = 0; i < 4; ++i)
#pragma unroll
            for (int rr = 0; rr < 4; ++rr) {
              const int row = r0 + i * 16 + rr;  // d index
              const float bb = bv[row];
#pragma unroll
              for (int j = 0; j < 4; ++j)
                Vtb[(size_t)row * 8192 + c0 + j * 16] = f2b(acc[i][j][rr] + bb);
            }
        });
  }
}

// lower-triangle tiles only: grid (136, 4); S stored bf16
__global__ __launch_bounds__(256) void score_kernel(const u16* __restrict__ Qb,
                                                    const u16* __restrict__ Kb,
                                                    u16* __restrict__ S) {
  const int b = blockIdx.y;
  const int t = blockIdx.x;
  int qt = 0;
  while ((qt + 1) * (qt + 2) / 2 <= t) ++qt;
  const int kt = t - (qt * (qt + 1)) / 2;
  const u16* A = Qb + ((size_t)b * 2048 + qt * 128) * 1024;
  const u16* Bp = Kb + ((size_t)b * 2048 + kt * 128) * 1024;
  u16* Sb = S + (size_t)b * 2048 * 2048;
  gemm_bt_tile(A, 1024, Bp, 1024, 16,
               [&](f32x4(&acc)[4][4], int wr, int wc, int lane) {
                 const int r0 = qt * 128 + wr + ((lane >> 4) << 2);
                 const int c0 = kt * 128 + wc + (lane & 15);
#pragma unroll
                 for (int i = 0; i < 4; ++i)
#pragma unroll
                   for (int j = 0; j < 4; ++j)
#pragma unroll
                     for (int rr = 0; rr < 4; ++rr)
                       Sb[(size_t)(r0 + i * 16 + rr) * 2048 + c0 + j * 16] =
                           f2b(acc[i][j][rr]);
               });
}

// one block per row; bf16 S in, bf16 P out; fully short8-vectorized.
__global__ __launch_bounds__(256) void softmax_kernel(const u16* __restrict__ S,
                                                      u16* __restrict__ P) {
  __shared__ float redm[4], reds[4];
  const int rowid = blockIdx.x;
  const int b = rowid >> 11;
  const int q = rowid & 2047;
  const u16* Srow = S + ((size_t)b * 2048 + q) * 2048;
  u16* Prow = P + ((size_t)b * 2048 + q) * 2048;
  const int L = q + 1;
  const int Lpad = ((q >> 7) + 1) << 7;
  const int tid = threadIdx.x;
  const int k0 = tid << 3;
  const bool active = k0 < Lpad;
  float v[8];
  float m = -1e30f;
  if (active) {
    const short8 s8 = *(const short8*)(Srow + k0);
#pragma unroll
    for (int j = 0; j < 8; ++j) {
      v[j] = (k0 + j < L) ? b2f((u16)s8[j]) : -1e30f;
      m = fmaxf(m, v[j]);
    }
  }
#pragma unroll
  for (int o = 32; o > 0; o >>= 1) m = fmaxf(m, __shfl_xor(m, o));
  if ((tid & 63) == 0) redm[tid >> 6] = m;
  __syncthreads();
  m = fmaxf(fmaxf(redm[0], redm[1]), fmaxf(redm[2], redm[3]));
  float s = 0.f;
  if (active) {
#pragma unroll
    for (int j = 0; j < 8; ++j) {
      const float e = (k0 + j < L) ? __expf(v[j] - m) : 0.f;
      v[j] = e;
      s += e;
    }
  }
#pragma unroll
  for (int o = 32; o > 0; o >>= 1) s += __shfl_xor(s, o);
  if ((tid & 63) == 0) reds[tid >> 6] = s;
  __syncthreads();
  s = reds[0] + reds[1] + reds[2] + reds[3];
  const float inv = 1.0f / s;
  if (active) {
    short8 o8;
#pragma unroll
    for (int j = 0; j < 8; ++j)
      o8[j] = (short)((k0 + j < L) ? f2b(v[j] * inv) : (u16)0);
    *(short8*)(Prow + k0) = o8;
  }
}

// O = P @ V using Vt[d][t]; K-loop truncated by causality; balanced grid.
__global__ __launch_bounds__(256) void pv_kernel(const u16* __restrict__ P,
                                                 const u16* __restrict__ Vtb,
                                                 float* __restrict__ O) {
  const int bid = blockIdx.x;  // 512
  const int pair = bid >> 8;
  const int idx = bid & 255;
  const int hb = idx >> 7;
  const int qt_raw = (idx >> 3) & 15;
  const int dt = idx & 7;
  const int qt = pair ? (15 - qt_raw) : qt_raw;
  const int b = pair * 2 + hb;
  const u16* A = P + (size_t)b * 2048 * 2048 + (size_t)qt * 128 * 2048;
  const u16* Bp = Vtb + (size_t)dt * 128 * 8192 + b * 2048;
  float* Ob = O + (size_t)b * 2048 * 1024;
  gemm_bt_tile(A, 2048, Bp, 8192, (qt + 1) * 2,
               [&](f32x4(&acc)[4][4], int wr, int wc, int lane) {
                 const int r0 = qt * 128 + wr + ((lane >> 4) << 2);
                 const int c0 = dt * 128 + wc + (lane & 15);
#pragma unroll
                 for (int i = 0; i < 4; ++i)
#pragma unroll
                   for (int j = 0; j < 4; ++j)
#pragma unroll
                     for (int rr = 0; rr < 4; ++rr)
                       Ob[(size_t)(r0 + i * 16 + rr) * 1024 + c0 + j * 16] =
                           acc[i][j][rr];
               });
}

extern "C" void kernel_launch(void* const* d_in, const int* in_sizes, int n_in,
                              void* d_out, int out_size, void* d_ws, size_t ws_size,
                              hipStream_t stream) {
  const float* x = (const float*)d_in[0];
  const float* Wq = (const float*)d_in[1];
  const float* bq = (const float*)d_in[2];
  const float* Wk = (const float*)d_in[3];
  const float* bk = (const float*)d_in[4];
  const float* Wv = (const float*)d_in[5];
  const float* bv = (const float*)d_in[6];
  float* out = (float*)d_out;
  char* ws = (char*)d_ws;
  u16* Qb = (u16*)(ws);
  u16* Kb = (u16*)(ws + (16u << 20));
  u16* Vtb = (u16*)(ws + (32u << 20));
  u16* xb = (u16*)(ws + (48u << 20));
  u16* Wcat = (u16*)(ws + (64u << 20));
  u16* S = (u16*)(ws + (70u << 20));
  u16* P = (u16*)(ws + (134u << 20));

  cvt_all_kernel<<<11264, 256, 0, stream>>>(x, Wq, Wk, Wv, xb, Wcat);
  qkv_kernel<<<1536, 256, 0, stream>>>(xb, Wcat, bq, bk, bv, Qb, Kb, Vtb);
  score_kernel<<<dim3(136, 4), 256, 0, stream>>>(Qb, Kb, S);
  softmax_kernel<<<8192, 256, 0, stream>>>(S, P);
  pv_kernel<<<512, 256, 0, stream>>>(P, Vtb, out);
}